// Round 11
// baseline (395.705 us; speedup 1.0000x reference)
//
#include <hip/hip_runtime.h>

typedef float f32x4 __attribute__((ext_vector_type(4)));
typedef __bf16 bf16x8 __attribute__((ext_vector_type(8)));
typedef unsigned short u16;
typedef unsigned int u32;
typedef u16 u16x4 __attribute__((ext_vector_type(4)));
typedef u16 u16x8 __attribute__((ext_vector_type(8)));
typedef u32 u32x4 __attribute__((ext_vector_type(4)));

#define DEV static __device__ __forceinline__

constexpr int B = 4, C = 512, NH = 8, HD = 64, NN = 4096, C3 = 1536;
constexpr float K_PRESCALE = 0.125f * 1.4426950408889634f;  // fold scale*log2e into K
constexpr float CLIP2 = 10.0f * 1.4426950408889634f;        // clip bound in exp2 domain

DEV u16 f2bf(float f) { union { __bf16 b; u16 s; } u; u.b = (__bf16)f; return u.s; }

#if __has_builtin(__builtin_amdgcn_exp2f)
DEV float fast_exp2(float x) { return __builtin_amdgcn_exp2f(x); }
#else
DEV float fast_exp2(float x) { return __expf(x * 0.6931471805599453f); }
#endif

#if __has_builtin(__builtin_amdgcn_fmed3f)
DEV float clamp2(float x) { return __builtin_amdgcn_fmed3f(x, -CLIP2, CLIP2); }
#else
DEV float clamp2(float x) { return fminf(fmaxf(x, -CLIP2), CLIP2); }
#endif

// ---------------- kernel 0a: x [B,C,N] f32 -> Xt [B,N,C] bf16 ----------------
__global__ __launch_bounds__(256) void k_transpose(const float* __restrict__ x,
                                                   u16* __restrict__ Xt) {
  __shared__ float tile[64][65];
  const int n0 = blockIdx.x * 64, c0 = blockIdx.y * 64, b = blockIdx.z;
  const int t = threadIdx.x;
  const int cl = t >> 4, n4 = (t & 15) * 4;
#pragma unroll
  for (int rep = 0; rep < 4; ++rep) {
    const int c = rep * 16 + cl;
    const f32x4 v = *(const f32x4*)(x + ((size_t)(b * C + c0 + c)) * NN + n0 + n4);
#pragma unroll
    for (int j = 0; j < 4; ++j) tile[c][n4 + j] = v[j];
  }
  __syncthreads();
#pragma unroll
  for (int rep = 0; rep < 16; ++rep) {
    const int n = rep * 4 + (t >> 6);
    const int c = t & 63;
    Xt[((size_t)(b * NN + n0 + n)) * C + c0 + c] = f2bf(tile[c][n]);
  }
}

// ---------------- kernel 0b: weights f32 -> bf16 ----------------
__global__ __launch_bounds__(256) void k_cvtw(const float* __restrict__ wq,
                                              const float* __restrict__ wp,
                                              u16* __restrict__ Wq, u16* __restrict__ Wp) {
  const int idx = blockIdx.x * 256 + threadIdx.x;
  const int NQ = C3 * C / 4;
  const float* src;
  u16* dst;
  int i4;
  if (idx < NQ) { src = wq; dst = Wq; i4 = idx; }
  else          { src = wp; dst = Wp; i4 = idx - NQ; }
  const f32x4 v = *(const f32x4*)(src + (size_t)i4 * 4);
  u16x4 o;
#pragma unroll
  for (int j = 0; j < 4; ++j) o[j] = f2bf(v[j]);
  *(u16x4*)(dst + (size_t)i4 * 4) = o;
}

// ---------------- kernel 1: QKV GEMM ----------------
// qkv[b][n][m] = sum_c Xt[b][n][c] * W[m][c] + bias[m]
// m<512 -> Q[b][h][n][d]; m<1024 -> K*presc[b][h][n][d]; else V^T[b][h][d][n]
__global__ __launch_bounds__(256) void k_qkv(const u16* __restrict__ Xt,
                                             const u16* __restrict__ W,
                                             const float* __restrict__ bias,
                                             u16* __restrict__ Q, u16* __restrict__ Kq,
                                             u16* __restrict__ Vt) {
  __shared__ u16 smem[16384];
  u16* Alds = smem;
  u16* Blds = smem + 8192;
  const int nt = blockIdx.x, mt = blockIdx.y, b = blockIdx.z;
  const int t = threadIdx.x, w = t >> 6, l = t & 63;
  const int l15 = l & 15, l4 = l >> 4;
  const int wr = w >> 1, wc = w & 1;
  f32x4 acc[4][4] = {};
  const u16* Abase = Xt + (size_t)(b * NN + nt * 128) * C;
  const u16* Bbase = W + (size_t)(mt * 128) * C;

  for (int kt = 0; kt < C / 64; ++kt) {
    __syncthreads();
#pragma unroll
    for (int i = 0; i < 4; ++i) {
      const int cch = t + 256 * i;
      const int r = cch >> 3, kb = (cch & 7) * 16;
      const int sw = kb ^ ((r & 7) << 4);
      *(f32x4*)((char*)Alds + r * 128 + sw) =
          *(const f32x4*)((const char*)(Abase + (size_t)r * C + kt * 64) + kb);
      *(f32x4*)((char*)Blds + r * 128 + sw) =
          *(const f32x4*)((const char*)(Bbase + (size_t)r * C + kt * 64) + kb);
    }
    __syncthreads();
#pragma unroll
    for (int ks = 0; ks < 2; ++ks) {
      bf16x8 af[4], bfr[4];
#pragma unroll
      for (int ri = 0; ri < 4; ++ri) {
        const int row = wr * 64 + ri * 16 + l15;
        af[ri] = *(const bf16x8*)((const char*)Alds + row * 128 +
                                  ((ks * 64 + l4 * 16) ^ ((row & 7) << 4)));
      }
#pragma unroll
      for (int cj = 0; cj < 4; ++cj) {
        const int row = wc * 64 + cj * 16 + l15;
        bfr[cj] = *(const bf16x8*)((const char*)Blds + row * 128 +
                                   ((ks * 64 + l4 * 16) ^ ((row & 7) << 4)));
      }
#pragma unroll
      for (int ri = 0; ri < 4; ++ri)
#pragma unroll
        for (int cj = 0; cj < 4; ++cj)
          acc[ri][cj] = __builtin_amdgcn_mfma_f32_16x16x32_bf16(af[ri], bfr[cj], acc[ri][cj], 0, 0, 0);
    }
  }

  // -------- epilogue: retile through LDS for coalesced stores --------
  __syncthreads();
  const int sec = mt >> 2;   // block-uniform: 0=Q 1=K 2=V
  const int mtl = mt & 3;
  if (sec < 2) {
    // smem[n_l 128][m_l 128] u16, swizzled on m-offset
#pragma unroll
    for (int ri = 0; ri < 4; ++ri)
#pragma unroll
      for (int cj = 0; cj < 4; ++cj) {
        const int m_l = wc * 64 + cj * 16 + l15;
        const float bv = bias[mt * 128 + m_l];
        const float sc = (sec == 1) ? K_PRESCALE : 1.0f;
#pragma unroll
        for (int r = 0; r < 4; ++r) {
          const int n_l = wr * 64 + ri * 16 + l4 * 4 + r;
          *(u16*)((char*)smem + n_l * 256 + ((m_l * 2) ^ ((n_l & 7) << 4))) =
              f2bf((acc[ri][cj][r] + bv) * sc);
        }
      }
    __syncthreads();
    u16* dst = (sec == 0) ? Q : Kq;
#pragma unroll
    for (int rep = 0; rep < 8; ++rep) {
      const int idx = rep * 256 + t;
      const int n_l = idx >> 4, ch = idx & 15;
      const u16x8 v = *(const u16x8*)((char*)smem + n_l * 256 + ((ch * 16) ^ ((n_l & 7) << 4)));
      const int hh = mtl * 2 + (ch >> 3), dd = (ch & 7) * 8;
      *(u16x8*)(dst + ((size_t)(b * NH + hh) * NN + nt * 128 + n_l) * HD + dd) = v;
    }
  } else {
    // smem[m_l 128][n_l 128] u16, swizzled on n-offset; u16x4 packed writes along n
#pragma unroll
    for (int ri = 0; ri < 4; ++ri)
#pragma unroll
      for (int cj = 0; cj < 4; ++cj) {
        const int m_l = wc * 64 + cj * 16 + l15;
        const float bv = bias[mt * 128 + m_l];
        const int nb = wr * 64 + ri * 16 + l4 * 4;
        u16x4 pv;
#pragma unroll
        for (int r = 0; r < 4; ++r) pv[r] = f2bf(acc[ri][cj][r] + bv);
        *(u16x4*)((char*)smem + m_l * 256 + ((nb * 2) ^ ((m_l & 7) << 4))) = pv;
      }
    __syncthreads();
#pragma unroll
    for (int rep = 0; rep < 8; ++rep) {
      const int idx = rep * 256 + t;
      const int m_l = idx >> 4, ch = idx & 15;
      const u16x8 v = *(const u16x8*)((char*)smem + m_l * 256 + ((ch * 16) ^ ((m_l & 7) << 4)));
      const int hh = mtl * 2 + (m_l >> 6), dd = m_l & 63;
      *(u16x8*)(Vt + ((size_t)(b * NH + hh) * HD + dd) * NN + nt * 128 + ch * 8) = v;
    }
  }
}

// ---------------- kernel 2: attention ----------------
// 64 q-rows per block (4 waves x 16 rows). K prescaled by 0.125*log2e.
// SWAPPED QK^T: s = mfma(K, Q) -> lane owns q = l15, 16 keys.
// P = exp2(med3(S)) stays in registers; PV A-fragments built via shfl
// (no P LDS roundtrip). K/V double-buffered, ONE barrier per iteration.
__global__ __launch_bounds__(256) void k_attn(const u16* __restrict__ Q,
                                              const u16* __restrict__ K,
                                              const u16* __restrict__ Vt,
                                              u16* __restrict__ AO) {
  __shared__ u16 Klds[2][4096];  // [buf][64 key][64 d]  swz  (2 x 8 KB)
  __shared__ u16 Vlds[2][4096];  // [buf][64 d][64 key]  swz  (2 x 8 KB)
  const int qt = blockIdx.x, h = blockIdx.y, b = blockIdx.z;
  const int bh = b * NH + h;
  const int t = threadIdx.x, w = t >> 6, l = t & 63;
  const int l15 = l & 15, l4 = l >> 4;
  const int q0 = qt * 64;

  // Q fragments in registers: q-col = w*16 + l15, d-steps {0,1}  (B-operand)
  const u16* qb = Q + ((size_t)bh * NN + q0 + w * 16 + l15) * HD + l4 * 8;
  bf16x8 qf[2];
  qf[0] = *(const bf16x8*)(qb);
  qf[1] = *(const bf16x8*)(qb + 32);

  f32x4 o[4] = {};   // PV accum: rows q=w*16+l4*4+r, cols d=cj*16+l15
  float rs = 0.f;    // per-lane softmax denom partial for q = w*16+l15

  // staging: lane handles rows sr and sr+32, one 16B chunk each, for K and V
  const int sr = t >> 3, scb = (t & 7) * 16;
  const int swoff = (scb ^ ((sr & 7) << 4)) + sr * 128;
  const char* kg = (const char*)(K + (size_t)bh * NN * HD) + sr * 128 + scb;
  const char* vg = (const char*)(Vt + (size_t)bh * HD * NN) + (size_t)sr * 8192 + scb;

  const int sw7 = (l15 & 7) << 4;  // fragment-read row-swizzle (row&7 == l15&7)

  // shfl lanes for building PV A-fragments
  const int addr_a = ((l & 16) << 1) + l15;  // 32*(l4&1) + l15
  const int addr_b = addr_a + 16;
  const bool sel_hi = (l & 32) != 0;         // l4 & 2

  // prologue: stage tile 0 into buffer 0
  {
    const f32x4 a0 = *(const f32x4*)kg;
    const f32x4 a1 = *(const f32x4*)(kg + 4096);
    const f32x4 a2 = *(const f32x4*)vg;
    const f32x4 a3 = *(const f32x4*)(vg + (size_t)32 * 8192);
    *(f32x4*)((char*)Klds + swoff) = a0;
    *(f32x4*)((char*)Klds + swoff + 4096) = a1;
    *(f32x4*)((char*)Vlds + swoff) = a2;
    *(f32x4*)((char*)Vlds + swoff + 4096) = a3;
  }
  __syncthreads();

  constexpr int NT = NN / 64;
  f32x4 kr0, kr1, vr0, vr1;
  for (int kv = 0; kv < NT; ++kv) {
    const int cur = kv & 1;
    const bool more = (kv + 1 < NT);
    if (more) {  // issue next tile's global loads early
      kg += 8192;
      vg += 128;
      kr0 = *(const f32x4*)kg;
      kr1 = *(const f32x4*)(kg + 4096);
      vr0 = *(const f32x4*)vg;
      vr1 = *(const f32x4*)(vg + (size_t)32 * 8192);
    }
    const char* kbase = (const char*)Klds + cur * 8192;
    const char* vbase = (const char*)Vlds + cur * 8192;

    // S^T = K Q^T : s[cj][r] = S[key = cj*16+l4*4+r][q = w*16+l15]
    f32x4 s[4] = {};
#pragma unroll
    for (int ks = 0; ks < 2; ++ks) {
#pragma unroll
      for (int cj = 0; cj < 4; ++cj) {
        const bf16x8 kf = *(const bf16x8*)(kbase + (cj * 16 + l15) * 128 +
                                           ((ks * 64 + l4 * 16) ^ sw7));
        s[cj] = __builtin_amdgcn_mfma_f32_16x16x32_bf16(kf, qf[ks], s[cj], 0, 0, 0);
      }
    }

    // P = exp2(med3(S)); pack to bf16 pairs in-register; accumulate row sum
    u32 w32v[8];
#pragma unroll
    for (int cj = 0; cj < 4; ++cj) {
      const float p0 = fast_exp2(clamp2(s[cj][0]));
      const float p1 = fast_exp2(clamp2(s[cj][1]));
      const float p2 = fast_exp2(clamp2(s[cj][2]));
      const float p3 = fast_exp2(clamp2(s[cj][3]));
      rs += (p0 + p1) + (p2 + p3);
      w32v[cj * 2 + 0] = (u32)f2bf(p0) | ((u32)f2bf(p1) << 16);
      w32v[cj * 2 + 1] = (u32)f2bf(p2) | ((u32)f2bf(p3) << 16);
    }

    // Build PV A-fragments: pa[ks] holds P[q=w*16+l15][key = ks*32 + l4*8 + 0..7]
    u32x4 pa32[2];
#pragma unroll
    for (int ks = 0; ks < 2; ++ks) {
      const u32 wh0 = sel_hi ? w32v[ks * 4 + 2] : w32v[ks * 4 + 0];
      const u32 wh1 = sel_hi ? w32v[ks * 4 + 3] : w32v[ks * 4 + 1];
      pa32[ks][0] = (u32)__shfl((int)wh0, addr_a, 64);
      pa32[ks][1] = (u32)__shfl((int)wh1, addr_a, 64);
      pa32[ks][2] = (u32)__shfl((int)wh0, addr_b, 64);
      pa32[ks][3] = (u32)__shfl((int)wh1, addr_b, 64);
    }

    // O += P V
#pragma unroll
    for (int ks = 0; ks < 2; ++ks) {
      union { u32x4 u; bf16x8 h; } pa;
      pa.u = pa32[ks];
#pragma unroll
      for (int cj = 0; cj < 4; ++cj) {
        const bf16x8 vf = *(const bf16x8*)(vbase + (cj * 16 + l15) * 128 +
                                           ((ks * 64 + l4 * 16) ^ sw7));
        o[cj] = __builtin_amdgcn_mfma_f32_16x16x32_bf16(pa.h, vf, o[cj], 0, 0, 0);
      }
    }

    // publish next tile into the other buffer (nobody reads it this iter)
    if (more) {
      char* kw = (char*)Klds + (cur ^ 1) * 8192 + swoff;
      char* vw = (char*)Vlds + (cur ^ 1) * 8192 + swoff;
      *(f32x4*)kw = kr0;
      *(f32x4*)(kw + 4096) = kr1;
      *(f32x4*)vw = vr0;
      *(f32x4*)(vw + 4096) = vr1;
    }
    __syncthreads();  // single barrier: next buffer visible AND cur reads done
  }

  // epilogue: total rowsum for q = w*16+l15 lives across lanes l15 + 16*{0..3}
  float v = rs;
  v += __shfl_xor(v, 16, 64);
  v += __shfl_xor(v, 32, 64);
  // redistribute: o-row r needs rowsum of q = w*16 + l4*4 + r (lane l15 = l4*4+r)
  float inv[4];
#pragma unroll
  for (int r = 0; r < 4; ++r)
    inv[r] = 1.0f / __shfl(v, (l & 48) | (((l >> 4) & 3) * 4 + r), 64);
#pragma unroll
  for (int cj = 0; cj < 4; ++cj)
#pragma unroll
    for (int r = 0; r < 4; ++r) {
      const int n = q0 + w * 16 + l4 * 4 + r;
      const int c = h * 64 + cj * 16 + l15;
      AO[((size_t)(b * NN + n)) * C + c] = f2bf(o[cj][r] * inv[r]);
    }
}

// ---------------- kernel 3: proj GEMM + bias + residual ----------------
// out[b][co][n] = x[b][co][n] + bias[co] + sum_ci AO[b][n][ci] * Wp[co][ci]
__global__ __launch_bounds__(256) void k_proj(const u16* __restrict__ AO,
                                              const u16* __restrict__ Wp,
                                              const float* __restrict__ bias,
                                              const float* __restrict__ x,
                                              float* __restrict__ out) {
  __shared__ u16 smem[16384];
  u16* Alds = smem;
  u16* Blds = smem + 8192;
  const int nt = blockIdx.x, ct = blockIdx.y, b = blockIdx.z;
  const int t = threadIdx.x, w = t >> 6, l = t & 63;
  const int l15 = l & 15, l4 = l >> 4;
  const int wr = w >> 1, wc = w & 1;
  f32x4 acc[4][4] = {};
  const u16* Abase = AO + (size_t)(b * NN + nt * 128) * C;
  const u16* Bbase = Wp + (size_t)(ct * 128) * C;

  for (int kt = 0; kt < C / 64; ++kt) {
    __syncthreads();
#pragma unroll
    for (int i = 0; i < 4; ++i) {
      const int cch = t + 256 * i;
      const int r = cch >> 3, kb = (cch & 7) * 16;
      const int sw = kb ^ ((r & 7) << 4);
      *(f32x4*)((char*)Alds + r * 128 + sw) =
          *(const f32x4*)((const char*)(Abase + (size_t)r * C + kt * 64) + kb);
      *(f32x4*)((char*)Blds + r * 128 + sw) =
          *(const f32x4*)((const char*)(Bbase + (size_t)r * C + kt * 64) + kb);
    }
    __syncthreads();
#pragma unroll
    for (int ks = 0; ks < 2; ++ks) {
      bf16x8 af[4], bfr[4];
#pragma unroll
      for (int ri = 0; ri < 4; ++ri) {
        const int row = wr * 64 + ri * 16 + l15;
        af[ri] = *(const bf16x8*)((const char*)Alds + row * 128 +
                                  ((ks * 64 + l4 * 16) ^ ((row & 7) << 4)));
      }
#pragma unroll
      for (int cj = 0; cj < 4; ++cj) {
        const int row = wc * 64 + cj * 16 + l15;
        bfr[cj] = *(const bf16x8*)((const char*)Blds + row * 128 +
                                   ((ks * 64 + l4 * 16) ^ ((row & 7) << 4)));
      }
#pragma unroll
      for (int ri = 0; ri < 4; ++ri)
#pragma unroll
        for (int cj = 0; cj < 4; ++cj)
          acc[ri][cj] = __builtin_amdgcn_mfma_f32_16x16x32_bf16(af[ri], bfr[cj], acc[ri][cj], 0, 0, 0);
    }
  }

  // -------- epilogue: two co-half passes through f32 LDS retile --------
  float* fs = (float*)smem;  // 64 co x 128 n
  __syncthreads();
#pragma unroll
  for (int p = 0; p < 2; ++p) {
    if (p) __syncthreads();
    if (wc == p) {
#pragma unroll
      for (int ri = 0; ri < 4; ++ri)
#pragma unroll
        for (int cj = 0; cj < 4; ++cj) {
          const int co = cj * 16 + l15;  // 0..63
          const float bv = bias[ct * 128 + p * 64 + co];
          const int nb = wr * 64 + ri * 16 + l4 * 4;
          f32x4 vv;
#pragma unroll
          for (int r = 0; r < 4; ++r) vv[r] = acc[ri][cj][r] + bv;
          *(f32x4*)((char*)fs + co * 512 + ((nb * 4) ^ ((co & 7) << 4))) = vv;
        }
    }
    __syncthreads();
#pragma unroll
    for (int rep = 0; rep < 8; ++rep) {
      const int idx = rep * 256 + t;
      const int co = idx >> 5, ch = idx & 31;
      f32x4 vv = *(const f32x4*)((char*)fs + co * 512 + ((ch * 16) ^ ((co & 7) << 4)));
      const size_t base = ((size_t)(b * C + ct * 128 + p * 64 + co)) * NN + nt * 128 + ch * 4;
      const f32x4 xr = *(const f32x4*)(x + base);
#pragma unroll
      for (int r = 0; r < 4; ++r) vv[r] += xr[r];
      *(f32x4*)(out + base) = vv;
    }
  }
}

extern "C" void kernel_launch(void* const* d_in, const int* in_sizes, int n_in,
                              void* d_out, int out_size, void* d_ws, size_t ws_size,
                              hipStream_t stream) {
  const float* x      = (const float*)d_in[0];
  const float* w_qkv  = (const float*)d_in[1];
  const float* b_qkv  = (const float*)d_in[2];
  const float* w_proj = (const float*)d_in[3];
  const float* b_proj = (const float*)d_in[4];
  float* out = (float*)d_out;
  char* ws = (char*)d_ws;

  const size_t SZ_XT = (size_t)B * NN * C * 2;        // 16 MB
  const size_t SZ_WQ = (size_t)C3 * C * 2;            // 1.5 MB
  const size_t SZ_WP = (size_t)C * C * 2;             // 0.5 MB
  const size_t SZ_QK = (size_t)B * NH * NN * HD * 2;  // 16 MB each

  u16* Xt = (u16*)(ws);
  u16* Wq = (u16*)(ws + SZ_XT);
  u16* Wp = (u16*)(ws + SZ_XT + SZ_WQ);
  u16* Qb = (u16*)(ws + SZ_XT + SZ_WQ + SZ_WP);
  u16* Kb = (u16*)(ws + SZ_XT + SZ_WQ + SZ_WP + SZ_QK);
  u16* Vt = (u16*)(ws + SZ_XT + SZ_WQ + SZ_WP + 2 * SZ_QK);
  u16* AO = Xt;  // Xt dead after k_qkv; reuse for attention output

  k_transpose<<<dim3(NN / 64, C / 64, B), 256, 0, stream>>>(x, Xt);
  k_cvtw<<<dim3((C3 * C + C * C) / 4 / 256), 256, 0, stream>>>(w_qkv, w_proj, Wq, Wp);
  k_qkv<<<dim3(NN / 128, C3 / 128, B), 256, 0, stream>>>(Xt, Wq, b_qkv, Qb, Kb, Vt);
  k_attn<<<dim3(NN / 64, NH, B), 256, 0, stream>>>(Qb, Kb, Vt, AO);
  k_proj<<<dim3(NN / 128, C / 128, B), 256, 0, stream>>>(AO, Wp, b_proj, x, out);
}

// Round 12
// 378.681 us; speedup vs baseline: 1.0450x; 1.0450x over previous
//
#include <hip/hip_runtime.h>

typedef float f32x4 __attribute__((ext_vector_type(4)));
typedef __bf16 bf16x8 __attribute__((ext_vector_type(8)));
typedef unsigned short u16;
typedef unsigned int u32;
typedef u16 u16x4 __attribute__((ext_vector_type(4)));
typedef u16 u16x8 __attribute__((ext_vector_type(8)));

#define DEV static __device__ __forceinline__

constexpr int B = 4, C = 512, NH = 8, HD = 64, NN = 4096, C3 = 1536;
constexpr float K_PRESCALE = 0.125f * 1.4426950408889634f;  // fold scale*log2e into K
constexpr float CLIP2 = 10.0f * 1.4426950408889634f;        // clip bound in exp2 domain

DEV u16 f2bf(float f) { union { __bf16 b; u16 s; } u; u.b = (__bf16)f; return u.s; }

#if __has_builtin(__builtin_amdgcn_exp2f)
DEV float fast_exp2(float x) { return __builtin_amdgcn_exp2f(x); }
#else
DEV float fast_exp2(float x) { return __expf(x * 0.6931471805599453f); }
#endif

#if __has_builtin(__builtin_amdgcn_fmed3f)
DEV float clamp2(float x) { return __builtin_amdgcn_fmed3f(x, -CLIP2, CLIP2); }
#else
DEV float clamp2(float x) { return fminf(fmaxf(x, -CLIP2), CLIP2); }
#endif

#if __has_builtin(__builtin_amdgcn_global_load_lds)
#define HAVE_GLL 1
DEV void gll16(const void* g, void* l) {
  __builtin_amdgcn_global_load_lds(
      (const __attribute__((address_space(1))) void*)g,
      (__attribute__((address_space(3))) void*)l, 16, 0, 0);
}
#else
#define HAVE_GLL 0
#endif

// ---------------- kernel 0a: x [B,C,N] f32 -> Xt [B,N,C] bf16 ----------------
__global__ __launch_bounds__(256) void k_transpose(const float* __restrict__ x,
                                                   u16* __restrict__ Xt) {
  __shared__ float tile[64][65];
  const int n0 = blockIdx.x * 64, c0 = blockIdx.y * 64, b = blockIdx.z;
  const int t = threadIdx.x;
  const int cl = t >> 4, n4 = (t & 15) * 4;
#pragma unroll
  for (int rep = 0; rep < 4; ++rep) {
    const int c = rep * 16 + cl;
    const f32x4 v = *(const f32x4*)(x + ((size_t)(b * C + c0 + c)) * NN + n0 + n4);
#pragma unroll
    for (int j = 0; j < 4; ++j) tile[c][n4 + j] = v[j];
  }
  __syncthreads();
#pragma unroll
  for (int rep = 0; rep < 16; ++rep) {
    const int n = rep * 4 + (t >> 6);
    const int c = t & 63;
    Xt[((size_t)(b * NN + n0 + n)) * C + c0 + c] = f2bf(tile[c][n]);
  }
}

// ---------------- kernel 0b: weights f32 -> bf16 ----------------
__global__ __launch_bounds__(256) void k_cvtw(const float* __restrict__ wq,
                                              const float* __restrict__ wp,
                                              u16* __restrict__ Wq, u16* __restrict__ Wp) {
  const int idx = blockIdx.x * 256 + threadIdx.x;
  const int NQ = C3 * C / 4;
  const float* src;
  u16* dst;
  int i4;
  if (idx < NQ) { src = wq; dst = Wq; i4 = idx; }
  else          { src = wp; dst = Wp; i4 = idx - NQ; }
  const f32x4 v = *(const f32x4*)(src + (size_t)i4 * 4);
  u16x4 o;
#pragma unroll
  for (int j = 0; j < 4; ++j) o[j] = f2bf(v[j]);
  *(u16x4*)(dst + (size_t)i4 * 4) = o;
}

// ---------------- kernel 1: QKV GEMM ----------------
// qkv[b][n][m] = sum_c Xt[b][n][c] * W[m][c] + bias[m]
// m<512 -> Q[b][h][n][d]; m<1024 -> K*presc[b][h][n][d]; else V^T[b][h][d][n]
__global__ __launch_bounds__(256) void k_qkv(const u16* __restrict__ Xt,
                                             const u16* __restrict__ W,
                                             const float* __restrict__ bias,
                                             u16* __restrict__ Q, u16* __restrict__ Kq,
                                             u16* __restrict__ Vt) {
  __shared__ u16 smem[16384];
  u16* Alds = smem;
  u16* Blds = smem + 8192;
  const int nt = blockIdx.x, mt = blockIdx.y, b = blockIdx.z;
  const int t = threadIdx.x, w = t >> 6, l = t & 63;
  const int l15 = l & 15, l4 = l >> 4;
  const int wr = w >> 1, wc = w & 1;
  f32x4 acc[4][4] = {};
  const u16* Abase = Xt + (size_t)(b * NN + nt * 128) * C;
  const u16* Bbase = W + (size_t)(mt * 128) * C;

  for (int kt = 0; kt < C / 64; ++kt) {
    __syncthreads();
#if HAVE_GLL
    // linear LDS dest (cch*16) + pre-swizzled global source; reads stay swizzled
#pragma unroll
    for (int i = 0; i < 4; ++i) {
      const int cch = t + 256 * i;
      const int r = cch >> 3;
      const int sc = ((cch & 7) * 16) ^ ((r & 7) << 4);
      gll16((const char*)(Abase + (size_t)r * C + kt * 64) + sc, (char*)Alds + cch * 16);
      gll16((const char*)(Bbase + (size_t)r * C + kt * 64) + sc, (char*)Blds + cch * 16);
    }
#else
#pragma unroll
    for (int i = 0; i < 4; ++i) {
      const int cch = t + 256 * i;
      const int r = cch >> 3, kb = (cch & 7) * 16;
      const int sw = kb ^ ((r & 7) << 4);
      *(f32x4*)((char*)Alds + r * 128 + sw) =
          *(const f32x4*)((const char*)(Abase + (size_t)r * C + kt * 64) + kb);
      *(f32x4*)((char*)Blds + r * 128 + sw) =
          *(const f32x4*)((const char*)(Bbase + (size_t)r * C + kt * 64) + kb);
    }
#endif
    __syncthreads();
#pragma unroll
    for (int ks = 0; ks < 2; ++ks) {
      bf16x8 af[4], bfr[4];
#pragma unroll
      for (int ri = 0; ri < 4; ++ri) {
        const int row = wr * 64 + ri * 16 + l15;
        af[ri] = *(const bf16x8*)((const char*)Alds + row * 128 +
                                  ((ks * 64 + l4 * 16) ^ ((row & 7) << 4)));
      }
#pragma unroll
      for (int cj = 0; cj < 4; ++cj) {
        const int row = wc * 64 + cj * 16 + l15;
        bfr[cj] = *(const bf16x8*)((const char*)Blds + row * 128 +
                                   ((ks * 64 + l4 * 16) ^ ((row & 7) << 4)));
      }
#pragma unroll
      for (int ri = 0; ri < 4; ++ri)
#pragma unroll
        for (int cj = 0; cj < 4; ++cj)
          acc[ri][cj] = __builtin_amdgcn_mfma_f32_16x16x32_bf16(af[ri], bfr[cj], acc[ri][cj], 0, 0, 0);
    }
  }

  // -------- epilogue: retile through LDS for coalesced stores --------
  __syncthreads();
  const int sec = mt >> 2;   // block-uniform: 0=Q 1=K 2=V
  const int mtl = mt & 3;
  if (sec < 2) {
    // smem[n_l 128][m_l 128] u16, swizzled on m-offset
#pragma unroll
    for (int ri = 0; ri < 4; ++ri)
#pragma unroll
      for (int cj = 0; cj < 4; ++cj) {
        const int m_l = wc * 64 + cj * 16 + l15;
        const float bv = bias[mt * 128 + m_l];
        const float sc = (sec == 1) ? K_PRESCALE : 1.0f;
#pragma unroll
        for (int r = 0; r < 4; ++r) {
          const int n_l = wr * 64 + ri * 16 + l4 * 4 + r;
          *(u16*)((char*)smem + n_l * 256 + ((m_l * 2) ^ ((n_l & 7) << 4))) =
              f2bf((acc[ri][cj][r] + bv) * sc);
        }
      }
    __syncthreads();
    u16* dst = (sec == 0) ? Q : Kq;
#pragma unroll
    for (int rep = 0; rep < 8; ++rep) {
      const int idx = rep * 256 + t;
      const int n_l = idx >> 4, ch = idx & 15;
      const u16x8 v = *(const u16x8*)((char*)smem + n_l * 256 + ((ch * 16) ^ ((n_l & 7) << 4)));
      const int hh = mtl * 2 + (ch >> 3), dd = (ch & 7) * 8;
      *(u16x8*)(dst + ((size_t)(b * NH + hh) * NN + nt * 128 + n_l) * HD + dd) = v;
    }
  } else {
    // smem[m_l 128][n_l 128] u16, swizzled on n-offset; u16x4 packed writes along n
#pragma unroll
    for (int ri = 0; ri < 4; ++ri)
#pragma unroll
      for (int cj = 0; cj < 4; ++cj) {
        const int m_l = wc * 64 + cj * 16 + l15;
        const float bv = bias[mt * 128 + m_l];
        const int nb = wr * 64 + ri * 16 + l4 * 4;
        u16x4 pv;
#pragma unroll
        for (int r = 0; r < 4; ++r) pv[r] = f2bf(acc[ri][cj][r] + bv);
        *(u16x4*)((char*)smem + m_l * 256 + ((nb * 2) ^ ((m_l & 7) << 4))) = pv;
      }
    __syncthreads();
#pragma unroll
    for (int rep = 0; rep < 8; ++rep) {
      const int idx = rep * 256 + t;
      const int m_l = idx >> 4, ch = idx & 15;
      const u16x8 v = *(const u16x8*)((char*)smem + m_l * 256 + ((ch * 16) ^ ((m_l & 7) << 4)));
      const int hh = mtl * 2 + (m_l >> 6), dd = m_l & 63;
      *(u16x8*)(Vt + ((size_t)(b * NH + hh) * HD + dd) * NN + nt * 128 + ch * 8) = v;
    }
  }
}

// ---------------- kernel 2: attention ----------------
// 64 q-rows per block (4 waves x 16 rows). K prescaled by 0.125*log2e:
// P = exp2(med3(S, +-CLIP2)). O = P V / rowsum(P); rowsum via ones-MFMA.
// Staging split: global->reg at loop top, reg->LDS after the PV barrier.
// P is wave-private (same wave writes and reads its 16 rows) -> NO barrier
// between the P-write and PV. TWO barriers per iteration.
__global__ __launch_bounds__(256) void k_attn(const u16* __restrict__ Q,
                                              const u16* __restrict__ K,
                                              const u16* __restrict__ Vt,
                                              u16* __restrict__ AO) {
  __shared__ u16 Klds[4096];   // [64 key][64 d]  swz  (8 KB)
  __shared__ u16 Vlds[4096];   // [64 d][64 key]  swz  (8 KB)
  __shared__ u16 Plds[4096];   // [64 q][64 key]  swz  (8 KB, wave-private rows)
  const int qt = blockIdx.x, h = blockIdx.y, b = blockIdx.z;
  const int bh = b * NH + h;
  const int t = threadIdx.x, w = t >> 6, l = t & 63;
  const int l15 = l & 15, l4 = l >> 4;
  const int q0 = qt * 64;

  // Q fragments in registers: rows q0 + w*16 + l15, k-steps {0,1}
  const u16* qb = Q + ((size_t)bh * NN + q0 + w * 16 + l15) * HD + l4 * 8;
  bf16x8 qf[2];
  qf[0] = *(const bf16x8*)(qb);
  qf[1] = *(const bf16x8*)(qb + 32);

  // all-ones bf16 fragment for the rowsum MFMA
  union { u16 s; __bf16 b; } ob;
  ob.s = 0x3F80;
  bf16x8 ones;
#pragma unroll
  for (int j = 0; j < 8; ++j) ones[j] = ob.b;

  f32x4 o[4] = {};   // PV accum: rows w*16+l4*4+r, cols cj*16+l15
  f32x4 rsa = {};    // rowsum accum (every col identical)

  // staging: lane handles rows sr and sr+32, one 16B chunk each, for K and V
  const int sr = t >> 3, scb = (t & 7) * 16;
  const int ssw = scb ^ ((sr & 7) << 4);
  char* kwp = (char*)Klds + sr * 128 + ssw;
  char* vwp = (char*)Vlds + sr * 128 + ssw;
  const char* kg = (const char*)(K + (size_t)bh * NN * HD) + sr * 128 + scb;
  const char* vg = (const char*)(Vt + (size_t)bh * HD * NN) + (size_t)sr * 8192 + scb;

  const int sw7 = (l15 & 7) << 4;  // fragment-read row-swizzle (row&7 == l15&7)

  // prologue: stage tile 0
  f32x4 kr0 = *(const f32x4*)kg;
  f32x4 kr1 = *(const f32x4*)(kg + 4096);
  f32x4 vr0 = *(const f32x4*)vg;
  f32x4 vr1 = *(const f32x4*)(vg + (size_t)32 * 8192);
  *(f32x4*)kwp = kr0;
  *(f32x4*)(kwp + 4096) = kr1;
  *(f32x4*)vwp = vr0;
  *(f32x4*)(vwp + 4096) = vr1;
  __syncthreads();

  constexpr int NT = NN / 64;
  for (int kv = 0; kv < NT; ++kv) {
    // issue next tile's global loads early; latency hides under compute
    if (kv + 1 < NT) {
      kg += 8192;
      vg += 128;
      kr0 = *(const f32x4*)kg;
      kr1 = *(const f32x4*)(kg + 4096);
      vr0 = *(const f32x4*)vg;
      vr1 = *(const f32x4*)(vg + (size_t)32 * 8192);
    }

    // S = Q K^T
    f32x4 s[4] = {};
#pragma unroll
    for (int ks = 0; ks < 2; ++ks) {
#pragma unroll
      for (int cj = 0; cj < 4; ++cj) {
        const bf16x8 kf = *(const bf16x8*)((const char*)Klds + (cj * 16 + l15) * 128 +
                                           ((ks * 64 + l4 * 16) ^ sw7));
        s[cj] = __builtin_amdgcn_mfma_f32_16x16x32_bf16(qf[ks], kf, s[cj], 0, 0, 0);
      }
    }
    // P = exp2(med3(S)); write P to LDS (bf16, swizzled). Wave-private rows:
    // same-wave DS ordering makes the PV reads below safe without a barrier.
#pragma unroll
    for (int cj = 0; cj < 4; ++cj) {
      const int colb = (cj * 16 + l15) * 2;
#pragma unroll
      for (int r = 0; r < 4; ++r) {
        const float p = fast_exp2(clamp2(s[cj][r]));
        const int row = w * 16 + l4 * 4 + r;
        *(u16*)((char*)Plds + row * 128 + (colb ^ ((row & 7) << 4))) = f2bf(p);
      }
    }

    // O += P V ; rsa += P * ones
#pragma unroll
    for (int ks = 0; ks < 2; ++ks) {
      const int prow = w * 16 + l15;
      const bf16x8 pa = *(const bf16x8*)((const char*)Plds + prow * 128 +
                                         ((ks * 64 + l4 * 16) ^ sw7));
#pragma unroll
      for (int cj = 0; cj < 4; ++cj) {
        const bf16x8 vf = *(const bf16x8*)((const char*)Vlds + (cj * 16 + l15) * 128 +
                                           ((ks * 64 + l4 * 16) ^ sw7));
        o[cj] = __builtin_amdgcn_mfma_f32_16x16x32_bf16(pa, vf, o[cj], 0, 0, 0);
      }
      rsa = __builtin_amdgcn_mfma_f32_16x16x32_bf16(pa, ones, rsa, 0, 0, 0);
    }
    __syncthreads();  // (a) all waves' K/V (and P) reads complete -> safe to overwrite

    if (kv + 1 < NT) {
      *(f32x4*)kwp = kr0;
      *(f32x4*)(kwp + 4096) = kr1;
      *(f32x4*)vwp = vr0;
      *(f32x4*)(vwp + 4096) = vr1;
    }
    __syncthreads();  // (b) next tile staged
  }

  // epilogue: divide by rowsums (rsa[r] is the full row sum; no shuffles needed)
  float inv[4];
#pragma unroll
  for (int r = 0; r < 4; ++r) inv[r] = 1.0f / rsa[r];
#pragma unroll
  for (int cj = 0; cj < 4; ++cj)
#pragma unroll
    for (int r = 0; r < 4; ++r) {
      const int n = q0 + w * 16 + l4 * 4 + r;
      const int c = h * 64 + cj * 16 + l15;
      AO[((size_t)(b * NN + n)) * C + c] = f2bf(o[cj][r] * inv[r]);
    }
}

// ---------------- kernel 3: proj GEMM + bias + residual ----------------
// out[b][co][n] = x[b][co][n] + bias[co] + sum_ci AO[b][n][ci] * Wp[co][ci]
__global__ __launch_bounds__(256) void k_proj(const u16* __restrict__ AO,
                                              const u16* __restrict__ Wp,
                                              const float* __restrict__ bias,
                                              const float* __restrict__ x,
                                              float* __restrict__ out) {
  __shared__ u16 smem[16384];
  u16* Alds = smem;
  u16* Blds = smem + 8192;
  const int nt = blockIdx.x, ct = blockIdx.y, b = blockIdx.z;
  const int t = threadIdx.x, w = t >> 6, l = t & 63;
  const int l15 = l & 15, l4 = l >> 4;
  const int wr = w >> 1, wc = w & 1;
  f32x4 acc[4][4] = {};
  const u16* Abase = AO + (size_t)(b * NN + nt * 128) * C;
  const u16* Bbase = Wp + (size_t)(ct * 128) * C;

  for (int kt = 0; kt < C / 64; ++kt) {
    __syncthreads();
#if HAVE_GLL
#pragma unroll
    for (int i = 0; i < 4; ++i) {
      const int cch = t + 256 * i;
      const int r = cch >> 3;
      const int sc = ((cch & 7) * 16) ^ ((r & 7) << 4);
      gll16((const char*)(Abase + (size_t)r * C + kt * 64) + sc, (char*)Alds + cch * 16);
      gll16((const char*)(Bbase + (size_t)r * C + kt * 64) + sc, (char*)Blds + cch * 16);
    }
#else
#pragma unroll
    for (int i = 0; i < 4; ++i) {
      const int cch = t + 256 * i;
      const int r = cch >> 3, kb = (cch & 7) * 16;
      const int sw = kb ^ ((r & 7) << 4);
      *(f32x4*)((char*)Alds + r * 128 + sw) =
          *(const f32x4*)((const char*)(Abase + (size_t)r * C + kt * 64) + kb);
      *(f32x4*)((char*)Blds + r * 128 + sw) =
          *(const f32x4*)((const char*)(Bbase + (size_t)r * C + kt * 64) + kb);
    }
#endif
    __syncthreads();
#pragma unroll
    for (int ks = 0; ks < 2; ++ks) {
      bf16x8 af[4], bfr[4];
#pragma unroll
      for (int ri = 0; ri < 4; ++ri) {
        const int row = wr * 64 + ri * 16 + l15;
        af[ri] = *(const bf16x8*)((const char*)Alds + row * 128 +
                                  ((ks * 64 + l4 * 16) ^ ((row & 7) << 4)));
      }
#pragma unroll
      for (int cj = 0; cj < 4; ++cj) {
        const int row = wc * 64 + cj * 16 + l15;
        bfr[cj] = *(const bf16x8*)((const char*)Blds + row * 128 +
                                   ((ks * 64 + l4 * 16) ^ ((row & 7) << 4)));
      }
#pragma unroll
      for (int ri = 0; ri < 4; ++ri)
#pragma unroll
        for (int cj = 0; cj < 4; ++cj)
          acc[ri][cj] = __builtin_amdgcn_mfma_f32_16x16x32_bf16(af[ri], bfr[cj], acc[ri][cj], 0, 0, 0);
    }
  }

  // -------- epilogue: two co-half passes through f32 LDS retile --------
  float* fs = (float*)smem;  // 64 co x 128 n
  __syncthreads();
#pragma unroll
  for (int p = 0; p < 2; ++p) {
    if (p) __syncthreads();
    if (wc == p) {
#pragma unroll
      for (int ri = 0; ri < 4; ++ri)
#pragma unroll
        for (int cj = 0; cj < 4; ++cj) {
          const int co = cj * 16 + l15;  // 0..63
          const float bv = bias[ct * 128 + p * 64 + co];
          const int nb = wr * 64 + ri * 16 + l4 * 4;
          f32x4 vv;
#pragma unroll
          for (int r = 0; r < 4; ++r) vv[r] = acc[ri][cj][r] + bv;
          *(f32x4*)((char*)fs + co * 512 + ((nb * 4) ^ ((co & 7) << 4))) = vv;
        }
    }
    __syncthreads();
#pragma unroll
    for (int rep = 0; rep < 8; ++rep) {
      const int idx = rep * 256 + t;
      const int co = idx >> 5, ch = idx & 31;
      f32x4 vv = *(const f32x4*)((char*)fs + co * 512 + ((ch * 16) ^ ((co & 7) << 4)));
      const size_t base = ((size_t)(b * C + ct * 128 + p * 64 + co)) * NN + nt * 128 + ch * 4;
      const f32x4 xr = *(const f32x4*)(x + base);
#pragma unroll
      for (int r = 0; r < 4; ++r) vv[r] += xr[r];
      *(f32x4*)(out + base) = vv;
    }
  }
}

extern "C" void kernel_launch(void* const* d_in, const int* in_sizes, int n_in,
                              void* d_out, int out_size, void* d_ws, size_t ws_size,
                              hipStream_t stream) {
  const float* x      = (const float*)d_in[0];
  const float* w_qkv  = (const float*)d_in[1];
  const float* b_qkv  = (const float*)d_in[2];
  const float* w_proj = (const float*)d_in[3];
  const float* b_proj = (const float*)d_in[4];
  float* out = (float*)d_out;
  char* ws = (char*)d_ws;

  const size_t SZ_XT = (size_t)B * NN * C * 2;        // 16 MB
  const size_t SZ_WQ = (size_t)C3 * C * 2;            // 1.5 MB
  const size_t SZ_WP = (size_t)C * C * 2;             // 0.5 MB
  const size_t SZ_QK = (size_t)B * NH * NN * HD * 2;  // 16 MB each

  u16* Xt = (u16*)(ws);
  u16* Wq = (u16*)(ws + SZ_XT);
  u16* Wp = (u16*)(ws + SZ_XT + SZ_WQ);
  u16* Qb = (u16*)(ws + SZ_XT + SZ_WQ + SZ_WP);
  u16* Kb = (u16*)(ws + SZ_XT + SZ_WQ + SZ_WP + SZ_QK);
  u16* Vt = (u16*)(ws + SZ_XT + SZ_WQ + SZ_WP + 2 * SZ_QK);
  u16* AO = Xt;  // Xt dead after k_qkv; reuse for attention output

  k_transpose<<<dim3(NN / 64, C / 64, B), 256, 0, stream>>>(x, Xt);
  k_cvtw<<<dim3((C3 * C + C * C) / 4 / 256), 256, 0, stream>>>(w_qkv, w_proj, Wq, Wp);
  k_qkv<<<dim3(NN / 128, C3 / 128, B), 256, 0, stream>>>(Xt, Wq, b_qkv, Qb, Kb, Vt);
  k_attn<<<dim3(NN / 64, NH, B), 256, 0, stream>>>(Qb, Kb, Vt, AO);
  k_proj<<<dim3(NN / 128, C / 128, B), 256, 0, stream>>>(AO, Wp, b_proj, x, out);
}

// Round 13
// 356.241 us; speedup vs baseline: 1.1108x; 1.0630x over previous
//
#include <hip/hip_runtime.h>

typedef float f32x4 __attribute__((ext_vector_type(4)));
typedef __bf16 bf16x8 __attribute__((ext_vector_type(8)));
typedef unsigned short u16;
typedef unsigned int u32;
typedef u16 u16x4 __attribute__((ext_vector_type(4)));
typedef u16 u16x8 __attribute__((ext_vector_type(8)));

#define DEV static __device__ __forceinline__

constexpr int B = 4, C = 512, NH = 8, HD = 64, NN = 4096, C3 = 1536;
constexpr float K_PRESCALE = 0.125f * 1.4426950408889634f;  // fold scale*log2e into K
constexpr float CLIP2 = 10.0f * 1.4426950408889634f;        // clip bound in exp2 domain

DEV u16 f2bf(float f) { union { __bf16 b; u16 s; } u; u.b = (__bf16)f; return u.s; }

#if __has_builtin(__builtin_amdgcn_exp2f)
DEV float fast_exp2(float x) { return __builtin_amdgcn_exp2f(x); }
#else
DEV float fast_exp2(float x) { return __expf(x * 0.6931471805599453f); }
#endif

#if __has_builtin(__builtin_amdgcn_fmed3f)
DEV float clamp2(float x) { return __builtin_amdgcn_fmed3f(x, -CLIP2, CLIP2); }
#else
DEV float clamp2(float x) { return fminf(fmaxf(x, -CLIP2), CLIP2); }
#endif

#if __has_builtin(__builtin_amdgcn_global_load_lds)
#define HAVE_GLL 1
DEV void gll16(const void* g, void* l) {
  __builtin_amdgcn_global_load_lds(
      (const __attribute__((address_space(1))) void*)g,
      (__attribute__((address_space(3))) void*)l, 16, 0, 0);
}
#else
#define HAVE_GLL 0
#endif

// ---------------- kernel 0a: x [B,C,N] f32 -> Xt [B,N,C] bf16 ----------------
__global__ __launch_bounds__(256) void k_transpose(const float* __restrict__ x,
                                                   u16* __restrict__ Xt) {
  __shared__ float tile[64][65];
  const int n0 = blockIdx.x * 64, c0 = blockIdx.y * 64, b = blockIdx.z;
  const int t = threadIdx.x;
  const int cl = t >> 4, n4 = (t & 15) * 4;
#pragma unroll
  for (int rep = 0; rep < 4; ++rep) {
    const int c = rep * 16 + cl;
    const f32x4 v = *(const f32x4*)(x + ((size_t)(b * C + c0 + c)) * NN + n0 + n4);
#pragma unroll
    for (int j = 0; j < 4; ++j) tile[c][n4 + j] = v[j];
  }
  __syncthreads();
#pragma unroll
  for (int rep = 0; rep < 16; ++rep) {
    const int n = rep * 4 + (t >> 6);
    const int c = t & 63;
    Xt[((size_t)(b * NN + n0 + n)) * C + c0 + c] = f2bf(tile[c][n]);
  }
}

// ---------------- kernel 0b: weights f32 -> bf16 ----------------
__global__ __launch_bounds__(256) void k_cvtw(const float* __restrict__ wq,
                                              const float* __restrict__ wp,
                                              u16* __restrict__ Wq, u16* __restrict__ Wp) {
  const int idx = blockIdx.x * 256 + threadIdx.x;
  const int NQ = C3 * C / 4;
  const float* src;
  u16* dst;
  int i4;
  if (idx < NQ) { src = wq; dst = Wq; i4 = idx; }
  else          { src = wp; dst = Wp; i4 = idx - NQ; }
  const f32x4 v = *(const f32x4*)(src + (size_t)i4 * 4);
  u16x4 o;
#pragma unroll
  for (int j = 0; j < 4; ++j) o[j] = f2bf(v[j]);
  *(u16x4*)(dst + (size_t)i4 * 4) = o;
}

// ---------------- kernel 1: QKV GEMM ----------------
// qkv[b][n][m] = sum_c Xt[b][n][c] * W[m][c] + bias[m]
// m<512 -> Q[b][h][n][d]; m<1024 -> K*presc[b][h][n][d]; else V^T[b][h][d][n]
__global__ __launch_bounds__(256) void k_qkv(const u16* __restrict__ Xt,
                                             const u16* __restrict__ W,
                                             const float* __restrict__ bias,
                                             u16* __restrict__ Q, u16* __restrict__ Kq,
                                             u16* __restrict__ Vt) {
  __shared__ u16 smem[16384];
  u16* Alds = smem;
  u16* Blds = smem + 8192;
  const int nt = blockIdx.x, mt = blockIdx.y, b = blockIdx.z;
  const int t = threadIdx.x, w = t >> 6, l = t & 63;
  const int l15 = l & 15, l4 = l >> 4;
  const int wr = w >> 1, wc = w & 1;
  f32x4 acc[4][4] = {};
  const u16* Abase = Xt + (size_t)(b * NN + nt * 128) * C;
  const u16* Bbase = W + (size_t)(mt * 128) * C;

  for (int kt = 0; kt < C / 64; ++kt) {
    __syncthreads();
#if HAVE_GLL
#pragma unroll
    for (int i = 0; i < 4; ++i) {
      const int cch = t + 256 * i;
      const int r = cch >> 3;
      const int sc = ((cch & 7) * 16) ^ ((r & 7) << 4);
      gll16((const char*)(Abase + (size_t)r * C + kt * 64) + sc, (char*)Alds + cch * 16);
      gll16((const char*)(Bbase + (size_t)r * C + kt * 64) + sc, (char*)Blds + cch * 16);
    }
#else
#pragma unroll
    for (int i = 0; i < 4; ++i) {
      const int cch = t + 256 * i;
      const int r = cch >> 3, kb = (cch & 7) * 16;
      const int sw = kb ^ ((r & 7) << 4);
      *(f32x4*)((char*)Alds + r * 128 + sw) =
          *(const f32x4*)((const char*)(Abase + (size_t)r * C + kt * 64) + kb);
      *(f32x4*)((char*)Blds + r * 128 + sw) =
          *(const f32x4*)((const char*)(Bbase + (size_t)r * C + kt * 64) + kb);
    }
#endif
    __syncthreads();
#pragma unroll
    for (int ks = 0; ks < 2; ++ks) {
      bf16x8 af[4], bfr[4];
#pragma unroll
      for (int ri = 0; ri < 4; ++ri) {
        const int row = wr * 64 + ri * 16 + l15;
        af[ri] = *(const bf16x8*)((const char*)Alds + row * 128 +
                                  ((ks * 64 + l4 * 16) ^ ((row & 7) << 4)));
      }
#pragma unroll
      for (int cj = 0; cj < 4; ++cj) {
        const int row = wc * 64 + cj * 16 + l15;
        bfr[cj] = *(const bf16x8*)((const char*)Blds + row * 128 +
                                   ((ks * 64 + l4 * 16) ^ ((row & 7) << 4)));
      }
#pragma unroll
      for (int ri = 0; ri < 4; ++ri)
#pragma unroll
        for (int cj = 0; cj < 4; ++cj)
          acc[ri][cj] = __builtin_amdgcn_mfma_f32_16x16x32_bf16(af[ri], bfr[cj], acc[ri][cj], 0, 0, 0);
    }
  }

  // -------- epilogue: retile through LDS for coalesced stores --------
  __syncthreads();
  const int sec = mt >> 2;   // block-uniform: 0=Q 1=K 2=V
  const int mtl = mt & 3;
  if (sec < 2) {
#pragma unroll
    for (int ri = 0; ri < 4; ++ri)
#pragma unroll
      for (int cj = 0; cj < 4; ++cj) {
        const int m_l = wc * 64 + cj * 16 + l15;
        const float bv = bias[mt * 128 + m_l];
        const float sc = (sec == 1) ? K_PRESCALE : 1.0f;
#pragma unroll
        for (int r = 0; r < 4; ++r) {
          const int n_l = wr * 64 + ri * 16 + l4 * 4 + r;
          *(u16*)((char*)smem + n_l * 256 + ((m_l * 2) ^ ((n_l & 7) << 4))) =
              f2bf((acc[ri][cj][r] + bv) * sc);
        }
      }
    __syncthreads();
    u16* dst = (sec == 0) ? Q : Kq;
#pragma unroll
    for (int rep = 0; rep < 8; ++rep) {
      const int idx = rep * 256 + t;
      const int n_l = idx >> 4, ch = idx & 15;
      const u16x8 v = *(const u16x8*)((char*)smem + n_l * 256 + ((ch * 16) ^ ((n_l & 7) << 4)));
      const int hh = mtl * 2 + (ch >> 3), dd = (ch & 7) * 8;
      *(u16x8*)(dst + ((size_t)(b * NH + hh) * NN + nt * 128 + n_l) * HD + dd) = v;
    }
  } else {
#pragma unroll
    for (int ri = 0; ri < 4; ++ri)
#pragma unroll
      for (int cj = 0; cj < 4; ++cj) {
        const int m_l = wc * 64 + cj * 16 + l15;
        const float bv = bias[mt * 128 + m_l];
        const int nb = wr * 64 + ri * 16 + l4 * 4;
        u16x4 pv;
#pragma unroll
        for (int r = 0; r < 4; ++r) pv[r] = f2bf(acc[ri][cj][r] + bv);
        *(u16x4*)((char*)smem + m_l * 256 + ((nb * 2) ^ ((m_l & 7) << 4))) = pv;
      }
    __syncthreads();
#pragma unroll
    for (int rep = 0; rep < 8; ++rep) {
      const int idx = rep * 256 + t;
      const int m_l = idx >> 4, ch = idx & 15;
      const u16x8 v = *(const u16x8*)((char*)smem + m_l * 256 + ((ch * 16) ^ ((m_l & 7) << 4)));
      const int hh = mtl * 2 + (m_l >> 6), dd = m_l & 63;
      *(u16x8*)(Vt + ((size_t)(b * NH + hh) * HD + dd) * NN + nt * 128 + ch * 8) = v;
    }
  }
}

// ---------------- kernel 2: attention ----------------
// 64 q-rows per block (4 waves x 16 rows). K prescaled by 0.125*log2e:
// P = exp2(med3(S)). O = P V / rowsum(P); rowsum via ones-MFMA.
// SPLIT-K DUAL STREAM: clip-softmax has no running max, so O and rowsum are
// pure sums over keys -> two independent key ranges (tiles kv and kv+32) are
// processed per iteration from separate LDS buffers into the SAME o/rsa.
// Two independent dependency chains per iter hide each other's latency;
// barriers halve per key-tile. Plds is shared (wave-private rows, same-wave
// DS ordering). 40 KB LDS -> 4 blocks/CU; VGPR capped at 128 (4 waves/SIMD).
__global__ __launch_bounds__(256, 4) void k_attn(const u16* __restrict__ Q,
                                                 const u16* __restrict__ K,
                                                 const u16* __restrict__ Vt,
                                                 u16* __restrict__ AO) {
  __shared__ u16 KldsA[4096];  // [64 key][64 d] swz (8 KB)
  __shared__ u16 VldsA[4096];  // [64 d][64 key] swz (8 KB)
  __shared__ u16 KldsB[4096];
  __shared__ u16 VldsB[4096];
  __shared__ u16 Plds[4096];   // [64 q][64 key] swz (8 KB, wave-private rows, shared A/B)
  const int qt = blockIdx.x, h = blockIdx.y, b = blockIdx.z;
  const int bh = b * NH + h;
  const int t = threadIdx.x, w = t >> 6, l = t & 63;
  const int l15 = l & 15, l4 = l >> 4;
  const int q0 = qt * 64;

  // Q fragments in registers: rows q0 + w*16 + l15, k-steps {0,1}
  const u16* qb = Q + ((size_t)bh * NN + q0 + w * 16 + l15) * HD + l4 * 8;
  bf16x8 qf[2];
  qf[0] = *(const bf16x8*)(qb);
  qf[1] = *(const bf16x8*)(qb + 32);

  // all-ones bf16 fragment for the rowsum MFMA
  union { u16 s; __bf16 b; } ob;
  ob.s = 0x3F80;
  bf16x8 ones;
#pragma unroll
  for (int j = 0; j < 8; ++j) ones[j] = ob.b;

  f32x4 o[4] = {};   // PV accum (both streams): rows w*16+l4*4+r, cols cj*16+l15
  f32x4 rsa = {};    // rowsum accum (both streams)

  // staging: lane handles rows sr and sr+32, one 16B chunk each, per K/V buffer
  const int sr = t >> 3, scb = (t & 7) * 16;
  const int so = sr * 128 + (scb ^ ((sr & 7) << 4));
  const char* kgA = (const char*)(K + (size_t)bh * NN * HD) + sr * 128 + scb;
  const char* vgA = (const char*)(Vt + (size_t)bh * HD * NN) + (size_t)sr * 8192 + scb;
  const char* kgB = kgA + (size_t)32 * 8192;   // key tile kv+32
  const char* vgB = vgA + 32 * 128;

  const int sw7 = (l15 & 7) << 4;  // fragment-read row-swizzle (row&7 == l15&7)

  // prologue: stage tile 0 (stream A) and tile 32 (stream B)
  {
    const f32x4 a0 = *(const f32x4*)kgA;
    const f32x4 a1 = *(const f32x4*)(kgA + 4096);
    const f32x4 a2 = *(const f32x4*)vgA;
    const f32x4 a3 = *(const f32x4*)(vgA + (size_t)32 * 8192);
    const f32x4 b0 = *(const f32x4*)kgB;
    const f32x4 b1 = *(const f32x4*)(kgB + 4096);
    const f32x4 b2 = *(const f32x4*)vgB;
    const f32x4 b3 = *(const f32x4*)(vgB + (size_t)32 * 8192);
    *(f32x4*)((char*)KldsA + so) = a0;
    *(f32x4*)((char*)KldsA + so + 4096) = a1;
    *(f32x4*)((char*)VldsA + so) = a2;
    *(f32x4*)((char*)VldsA + so + 4096) = a3;
    *(f32x4*)((char*)KldsB + so) = b0;
    *(f32x4*)((char*)KldsB + so + 4096) = b1;
    *(f32x4*)((char*)VldsB + so) = b2;
    *(f32x4*)((char*)VldsB + so + 4096) = b3;
  }
  __syncthreads();

  constexpr int NT2 = NN / 128;  // 32 iterations, 2 tiles each
  f32x4 ka0, ka1, va0, va1, kb0, kb1, vb0, vb1;
  for (int kv = 0; kv < NT2; ++kv) {
    const bool more = (kv + 1 < NT2);
    if (more) {  // issue next iteration's global loads early (both streams)
      kgA += 8192; vgA += 128; kgB += 8192; vgB += 128;
      ka0 = *(const f32x4*)kgA;
      ka1 = *(const f32x4*)(kgA + 4096);
      va0 = *(const f32x4*)vgA;
      va1 = *(const f32x4*)(vgA + (size_t)32 * 8192);
      kb0 = *(const f32x4*)kgB;
      kb1 = *(const f32x4*)(kgB + 4096);
      vb0 = *(const f32x4*)vgB;
      vb1 = *(const f32x4*)(vgB + (size_t)32 * 8192);
    }

#pragma unroll
    for (int st = 0; st < 2; ++st) {
      const char* kbase = st ? (const char*)KldsB : (const char*)KldsA;
      const char* vbase = st ? (const char*)VldsB : (const char*)VldsA;

      // S = Q K^T
      f32x4 s[4] = {};
#pragma unroll
      for (int ks = 0; ks < 2; ++ks) {
#pragma unroll
        for (int cj = 0; cj < 4; ++cj) {
          const bf16x8 kf = *(const bf16x8*)(kbase + (cj * 16 + l15) * 128 +
                                             ((ks * 64 + l4 * 16) ^ sw7));
          s[cj] = __builtin_amdgcn_mfma_f32_16x16x32_bf16(qf[ks], kf, s[cj], 0, 0, 0);
        }
      }
      // P = exp2(med3(S)) -> LDS (wave-private rows; no barrier needed)
#pragma unroll
      for (int cj = 0; cj < 4; ++cj) {
        const int colb = (cj * 16 + l15) * 2;
#pragma unroll
        for (int r = 0; r < 4; ++r) {
          const float p = fast_exp2(clamp2(s[cj][r]));
          const int row = w * 16 + l4 * 4 + r;
          *(u16*)((char*)Plds + row * 128 + (colb ^ ((row & 7) << 4))) = f2bf(p);
        }
      }
      // O += P V ; rsa += P * ones
#pragma unroll
      for (int ks = 0; ks < 2; ++ks) {
        const int prow = w * 16 + l15;
        const bf16x8 pa = *(const bf16x8*)((const char*)Plds + prow * 128 +
                                           ((ks * 64 + l4 * 16) ^ sw7));
#pragma unroll
        for (int cj = 0; cj < 4; ++cj) {
          const bf16x8 vf = *(const bf16x8*)(vbase + (cj * 16 + l15) * 128 +
                                             ((ks * 64 + l4 * 16) ^ sw7));
          o[cj] = __builtin_amdgcn_mfma_f32_16x16x32_bf16(pa, vf, o[cj], 0, 0, 0);
        }
        rsa = __builtin_amdgcn_mfma_f32_16x16x32_bf16(pa, ones, rsa, 0, 0, 0);
      }
    }

    __syncthreads();  // (a) all waves' K/V/P reads complete -> safe to overwrite
    if (more) {
      *(f32x4*)((char*)KldsA + so) = ka0;
      *(f32x4*)((char*)KldsA + so + 4096) = ka1;
      *(f32x4*)((char*)VldsA + so) = va0;
      *(f32x4*)((char*)VldsA + so + 4096) = va1;
      *(f32x4*)((char*)KldsB + so) = kb0;
      *(f32x4*)((char*)KldsB + so + 4096) = kb1;
      *(f32x4*)((char*)VldsB + so) = vb0;
      *(f32x4*)((char*)VldsB + so + 4096) = vb1;
    }
    __syncthreads();  // (b) next tiles staged
  }

  // epilogue: divide by rowsums (rsa[r] is the full row sum)
  float inv[4];
#pragma unroll
  for (int r = 0; r < 4; ++r) inv[r] = 1.0f / rsa[r];
#pragma unroll
  for (int cj = 0; cj < 4; ++cj)
#pragma unroll
    for (int r = 0; r < 4; ++r) {
      const int n = q0 + w * 16 + l4 * 4 + r;
      const int c = h * 64 + cj * 16 + l15;
      AO[((size_t)(b * NN + n)) * C + c] = f2bf(o[cj][r] * inv[r]);
    }
}

// ---------------- kernel 3: proj GEMM + bias + residual ----------------
// out[b][co][n] = x[b][co][n] + bias[co] + sum_ci AO[b][n][ci] * Wp[co][ci]
__global__ __launch_bounds__(256) void k_proj(const u16* __restrict__ AO,
                                              const u16* __restrict__ Wp,
                                              const float* __restrict__ bias,
                                              const float* __restrict__ x,
                                              float* __restrict__ out) {
  __shared__ u16 smem[16384];
  u16* Alds = smem;
  u16* Blds = smem + 8192;
  const int nt = blockIdx.x, ct = blockIdx.y, b = blockIdx.z;
  const int t = threadIdx.x, w = t >> 6, l = t & 63;
  const int l15 = l & 15, l4 = l >> 4;
  const int wr = w >> 1, wc = w & 1;
  f32x4 acc[4][4] = {};
  const u16* Abase = AO + (size_t)(b * NN + nt * 128) * C;
  const u16* Bbase = Wp + (size_t)(ct * 128) * C;

  for (int kt = 0; kt < C / 64; ++kt) {
    __syncthreads();
#if HAVE_GLL
#pragma unroll
    for (int i = 0; i < 4; ++i) {
      const int cch = t + 256 * i;
      const int r = cch >> 3;
      const int sc = ((cch & 7) * 16) ^ ((r & 7) << 4);
      gll16((const char*)(Abase + (size_t)r * C + kt * 64) + sc, (char*)Alds + cch * 16);
      gll16((const char*)(Bbase + (size_t)r * C + kt * 64) + sc, (char*)Blds + cch * 16);
    }
#else
#pragma unroll
    for (int i = 0; i < 4; ++i) {
      const int cch = t + 256 * i;
      const int r = cch >> 3, kb = (cch & 7) * 16;
      const int sw = kb ^ ((r & 7) << 4);
      *(f32x4*)((char*)Alds + r * 128 + sw) =
          *(const f32x4*)((const char*)(Abase + (size_t)r * C + kt * 64) + kb);
      *(f32x4*)((char*)Blds + r * 128 + sw) =
          *(const f32x4*)((const char*)(Bbase + (size_t)r * C + kt * 64) + kb);
    }
#endif
    __syncthreads();
#pragma unroll
    for (int ks = 0; ks < 2; ++ks) {
      bf16x8 af[4], bfr[4];
#pragma unroll
      for (int ri = 0; ri < 4; ++ri) {
        const int row = wr * 64 + ri * 16 + l15;
        af[ri] = *(const bf16x8*)((const char*)Alds + row * 128 +
                                  ((ks * 64 + l4 * 16) ^ ((row & 7) << 4)));
      }
#pragma unroll
      for (int cj = 0; cj < 4; ++cj) {
        const int row = wc * 64 + cj * 16 + l15;
        bfr[cj] = *(const bf16x8*)((const char*)Blds + row * 128 +
                                   ((ks * 64 + l4 * 16) ^ ((row & 7) << 4)));
      }
#pragma unroll
      for (int ri = 0; ri < 4; ++ri)
#pragma unroll
        for (int cj = 0; cj < 4; ++cj)
          acc[ri][cj] = __builtin_amdgcn_mfma_f32_16x16x32_bf16(af[ri], bfr[cj], acc[ri][cj], 0, 0, 0);
    }
  }

  // -------- epilogue: two co-half passes through f32 LDS retile --------
  float* fs = (float*)smem;  // 64 co x 128 n
  __syncthreads();
#pragma unroll
  for (int p = 0; p < 2; ++p) {
    if (p) __syncthreads();
    if (wc == p) {
#pragma unroll
      for (int ri = 0; ri < 4; ++ri)
#pragma unroll
        for (int cj = 0; cj < 4; ++cj) {
          const int co = cj * 16 + l15;  // 0..63
          const float bv = bias[ct * 128 + p * 64 + co];
          const int nb = wr * 64 + ri * 16 + l4 * 4;
          f32x4 vv;
#pragma unroll
          for (int r = 0; r < 4; ++r) vv[r] = acc[ri][cj][r] + bv;
          *(f32x4*)((char*)fs + co * 512 + ((nb * 4) ^ ((co & 7) << 4))) = vv;
        }
    }
    __syncthreads();
#pragma unroll
    for (int rep = 0; rep < 8; ++rep) {
      const int idx = rep * 256 + t;
      const int co = idx >> 5, ch = idx & 31;
      f32x4 vv = *(const f32x4*)((char*)fs + co * 512 + ((ch * 16) ^ ((co & 7) << 4)));
      const size_t base = ((size_t)(b * C + ct * 128 + p * 64 + co)) * NN + nt * 128 + ch * 4;
      const f32x4 xr = *(const f32x4*)(x + base);
#pragma unroll
      for (int r = 0; r < 4; ++r) vv[r] += xr[r];
      *(f32x4*)(out + base) = vv;
    }
  }
}

extern "C" void kernel_launch(void* const* d_in, const int* in_sizes, int n_in,
                              void* d_out, int out_size, void* d_ws, size_t ws_size,
                              hipStream_t stream) {
  const float* x      = (const float*)d_in[0];
  const float* w_qkv  = (const float*)d_in[1];
  const float* b_qkv  = (const float*)d_in[2];
  const float* w_proj = (const float*)d_in[3];
  const float* b_proj = (const float*)d_in[4];
  float* out = (float*)d_out;
  char* ws = (char*)d_ws;

  const size_t SZ_XT = (size_t)B * NN * C * 2;        // 16 MB
  const size_t SZ_WQ = (size_t)C3 * C * 2;            // 1.5 MB
  const size_t SZ_WP = (size_t)C * C * 2;             // 0.5 MB
  const size_t SZ_QK = (size_t)B * NH * NN * HD * 2;  // 16 MB each

  u16* Xt = (u16*)(ws);
  u16* Wq = (u16*)(ws + SZ_XT);
  u16* Wp = (u16*)(ws + SZ_XT + SZ_WQ);
  u16* Qb = (u16*)(ws + SZ_XT + SZ_WQ + SZ_WP);
  u16* Kb = (u16*)(ws + SZ_XT + SZ_WQ + SZ_WP + SZ_QK);
  u16* Vt = (u16*)(ws + SZ_XT + SZ_WQ + SZ_WP + 2 * SZ_QK);
  u16* AO = Xt;  // Xt dead after k_qkv; reuse for attention output

  k_transpose<<<dim3(NN / 64, C / 64, B), 256, 0, stream>>>(x, Xt);
  k_cvtw<<<dim3((C3 * C + C * C) / 4 / 256), 256, 0, stream>>>(w_qkv, w_proj, Wq, Wp);
  k_qkv<<<dim3(NN / 128, C3 / 128, B), 256, 0, stream>>>(Xt, Wq, b_qkv, Qb, Kb, Vt);
  k_attn<<<dim3(NN / 64, NH, B), 256, 0, stream>>>(Qb, Kb, Vt, AO);
  k_proj<<<dim3(NN / 128, C / 128, B), 256, 0, stream>>>(AO, Wp, b_proj, x, out);
}